// Round 7
// baseline (414.082 us; speedup 1.0000x reference)
//
#include <hip/hip_runtime.h>
#include <hip/hip_bf16.h>

#define EMBED  2048
#define SEQ    2048
#define BATCH  2
#define NHEADS 16
#define HDIM   128
#define QKVC   (3*EMBED)    // 6144
#define ROWS   (BATCH*SEQ)  // 4096

typedef __attribute__((ext_vector_type(8))) short bf16x8;
typedef __attribute__((ext_vector_type(4))) float f32x4;
typedef __attribute__((ext_vector_type(16))) float f32x16;

typedef const __attribute__((address_space(1))) void* gptr1_t;
typedef __attribute__((address_space(3))) void* lptr3_t;

__device__ __forceinline__ void gld16(const unsigned short* g, unsigned short* l) {
  __builtin_amdgcn_global_load_lds((gptr1_t)g, (lptr3_t)l, 16, 0, 0);
}

__device__ __forceinline__ unsigned short f2bf(float f) {
  unsigned int x = __float_as_uint(f);
  unsigned int r = (x + 0x7fffu + ((x >> 16) & 1u)) >> 16;
  return (unsigned short)r;
}

// ---------------- cast x -> bf16 ----------------
__global__ void cast_kernel(const float* __restrict__ in, unsigned short* __restrict__ out, int n4) {
  int i = blockIdx.x * 256 + threadIdx.x;
  if (i >= n4) return;
  float4 v = reinterpret_cast<const float4*>(in)[i];
  ushort4 o;
  o.x = f2bf(v.x); o.y = f2bf(v.y); o.z = f2bf(v.z); o.w = f2bf(v.w);
  reinterpret_cast<ushort4*>(out)[i] = o;
}

// ---------------- transpose + cast W [R][C] f32 -> [C][R] bf16 ----------------
__global__ void transpose_cast_kernel(const float* __restrict__ in, unsigned short* __restrict__ out,
                                      int R, int C) {
  __shared__ float tile[32][33];
  int tx = threadIdx.x & 31, ty = threadIdx.x >> 5;   // 32 x 8
  int c0 = blockIdx.x * 32, r0 = blockIdx.y * 32;
  #pragma unroll
  for (int i = 0; i < 32; i += 8)
    tile[ty + i][tx] = in[(size_t)(r0 + ty + i) * C + c0 + tx];
  __syncthreads();
  #pragma unroll
  for (int i = 0; i < 32; i += 8)
    out[(size_t)(c0 + ty + i) * R + r0 + tx] = f2bf(tile[tx][ty + i]);
}

// ---------------- MFMA GEMM (32x32x16 core, BK=64): C = A * BT^T + bias ----------
// 128x128 tile, BK=64 staged as two 128x32 XOR-swizzled sub-tiles. 16 MFMA/K-iter.
template<int MODE>
__global__ __launch_bounds__(256)
void gemm_kernel(const unsigned short* __restrict__ A,
                 const unsigned short* __restrict__ BT,
                 const float* __restrict__ bias,
                 unsigned short* __restrict__ outb,
                 unsigned short* __restrict__ vt,
                 float* __restrict__ outf,
                 int M, int N, int K) {
  __shared__ unsigned short As[2 * 128 * 32];
  __shared__ unsigned short Bs[2 * 128 * 32];
  const int t = threadIdx.x;
  const int lane = t & 63, wave = t >> 6;
  const int l31 = lane & 31, hl = lane >> 5;
  const int wm = wave >> 1, wn = wave & 1;
  const int m0 = blockIdx.y * 128, n0 = blockIdx.x * 128;

  f32x16 acc[2][2] = {};

  int aoff[2][4], boff[2][4];
  #pragma unroll
  for (int i = 0; i < 2; ++i) {
    int m = wm * 64 + i * 32 + l31;
    int pm = ((m >> 2) ^ m) & 3;
    int n = wn * 64 + i * 32 + l31;
    int pn = ((n >> 2) ^ n) & 3;
    #pragma unroll
    for (int s4 = 0; s4 < 4; ++s4) {
      int st = s4 >> 1, c = (s4 & 1) * 2 + hl;
      aoff[i][s4] = st * 4096 + (m * 4 + (c ^ pm)) * 8;
      boff[i][s4] = st * 4096 + (n * 4 + (c ^ pn)) * 8;
    }
  }
  int ldso[4];
  const unsigned short* Ag[4];
  const unsigned short* Bg[4];
  #pragma unroll
  for (int i = 0; i < 4; ++i) {
    int cc = i * 256 + t;
    int st = cc >> 9, w = cc & 511;
    int r = w >> 2, s = w & 3;
    int d = s ^ (((r >> 2) ^ r) & 3);
    ldso[i] = st * 4096 + w * 8;
    Ag[i] = A  + (size_t)(m0 + r) * K + st * 32 + d * 8;
    Bg[i] = BT + (size_t)(n0 + r) * K + st * 32 + d * 8;
  }

  for (int k0 = 0; k0 < K; k0 += 64) {
    #pragma unroll
    for (int i = 0; i < 4; ++i) gld16(Ag[i] + k0, &As[ldso[i]]);
    #pragma unroll
    for (int i = 0; i < 4; ++i) gld16(Bg[i] + k0, &Bs[ldso[i]]);
    __syncthreads();
    #pragma unroll
    for (int s4 = 0; s4 < 4; ++s4) {
      bf16x8 a0 = *(const bf16x8*)&As[aoff[0][s4]];
      bf16x8 a1 = *(const bf16x8*)&As[aoff[1][s4]];
      bf16x8 b0 = *(const bf16x8*)&Bs[boff[0][s4]];
      bf16x8 b1 = *(const bf16x8*)&Bs[boff[1][s4]];
      acc[0][0] = __builtin_amdgcn_mfma_f32_32x32x16_bf16(a0, b0, acc[0][0], 0, 0, 0);
      acc[0][1] = __builtin_amdgcn_mfma_f32_32x32x16_bf16(a0, b1, acc[0][1], 0, 0, 0);
      acc[1][0] = __builtin_amdgcn_mfma_f32_32x32x16_bf16(a1, b0, acc[1][0], 0, 0, 0);
      acc[1][1] = __builtin_amdgcn_mfma_f32_32x32x16_bf16(a1, b1, acc[1][1], 0, 0, 0);
    }
    __syncthreads();
  }

  #pragma unroll
  for (int i = 0; i < 2; ++i) {
    int rowb = m0 + wm * 64 + i * 32 + 4 * hl;
    #pragma unroll
    for (int j = 0; j < 2; ++j) {
      int col = n0 + wn * 64 + j * 32 + l31;
      float bv = bias[col];
      if (MODE == 1) {
        #pragma unroll
        for (int g = 0; g < 4; ++g)
          #pragma unroll
          for (int rr = 0; rr < 4; ++rr)
            outf[(size_t)(rowb + 8 * g + rr) * N + col] = acc[i][j][4 * g + rr] + bv;
      } else if (n0 < 2 * EMBED) {
        #pragma unroll
        for (int g = 0; g < 4; ++g)
          #pragma unroll
          for (int rr = 0; rr < 4; ++rr)
            outb[(size_t)(rowb + 8 * g + rr) * 4096 + col] = f2bf(acc[i][j][4 * g + rr] + bv);
      } else {
        int hd = col - 2 * EMBED;
        int b = rowb >> 11;
        int sbase = rowb & 2047;
        #pragma unroll
        for (int g = 0; g < 4; ++g) {
          ushort4 w;
          w.x = f2bf(acc[i][j][4 * g + 0] + bv);
          w.y = f2bf(acc[i][j][4 * g + 1] + bv);
          w.z = f2bf(acc[i][j][4 * g + 2] + bv);
          w.w = f2bf(acc[i][j][4 * g + 3] + bv);
          *(ushort4*)&vt[(((size_t)(b << 11) + hd) << 11) + sbase + 8 * g] = w;
        }
      }
    }
  }
}

// ---------------- flash attention (S^T form, merged-pair single KV sweep) ---------
// Block handles q-tiles A=pair and B=31-pair with ONE sweep over kv tiles 0..31-pair:
// tile A is computed only while j <= pair (its KV range is a subset of B's).
// grid: (x=32 bh, y=16 pairs) -> same-bh blocks on same XCD (linear id mod 8)
__global__ __launch_bounds__(256)
void attn_kernel(const unsigned short* __restrict__ qk,   // [4096][4096] Q|K bf16
                 const unsigned short* __restrict__ vt,   // [32*128][2048] V^T bf16
                 unsigned short* __restrict__ outb) {     // [4096][2048] bf16
  __shared__ unsigned short Ks[2][64 * 128];
  __shared__ unsigned short Vs[2][64 * 128];
  __shared__ unsigned short Ps[4][16 * 72];
  const int t = threadIdx.x;
  const int lane = t & 63, wave = t >> 6;
  const int quad = lane >> 4, l16 = lane & 15;
  const int bh = blockIdx.x;
  const int pair = blockIdx.y;
  const int b = bh >> 4, h = bh & 15;
  const size_t rowbase = (size_t)b * SEQ;
  const int hq = h * HDIM;
  const unsigned short* vbase = vt + ((size_t)bh * HDIM) * SEQ;

  const float SC = 0.08838834764831845f * 1.4426950408889634f; // 1/sqrt(128)*log2(e)

  const int qtA = pair, qtB = 31 - pair;
  const int qw0A = qtA * 64 + wave * 16;
  const int qw0B = qtB * 64 + wave * 16;

  // Q fragments (B-operand): lane n = l16 = q, k = s*32 + quad*8 + j
  bf16x8 qfA[4], qfB[4];
  {
    const unsigned short* qrA = qk + (size_t)(rowbase + qw0A + l16) * 4096 + hq + quad * 8;
    const unsigned short* qrB = qk + (size_t)(rowbase + qw0B + l16) * 4096 + hq + quad * 8;
    #pragma unroll
    for (int s = 0; s < 4; ++s) { qfA[s] = *(const bf16x8*)(qrA + s * 32); qfB[s] = *(const bf16x8*)(qrB + s * 32); }
  }

  f32x4 oA[8] = {}, oB[8] = {};
  float mA = -1e30f, lA = 0.f, mB = -1e30f, lB = 0.f;

  // prologue: stage tile 0 into buffer 0
  #pragma unroll
  for (int i = 0; i < 4; ++i) {
    int cc = i * 256 + t;
    int kv = cc >> 4, sc = cc & 15;
    int dc = sc ^ (kv & 15);
    gld16(qk + (size_t)(rowbase + kv) * 4096 + EMBED + hq + dc * 8, &Ks[0][cc * 8]);
  }
  #pragma unroll
  for (int i = 0; i < 4; ++i) {
    int cc = i * 256 + t;
    int d = cc >> 3, c = cc & 7;
    int dc = c ^ (d & 7);
    gld16(vbase + (size_t)d * SEQ + dc * 8, &Vs[0][cc * 8]);
  }

  // one q-tile's S/softmax/PV against the currently staged KV tile
  auto process = [&](int j, int cur, int kv0, const bf16x8* qf, f32x4* o,
                     float& mrow, float& lrow, int qt, int qw0) {
    f32x4 sacc[4] = {};
    #pragma unroll
    for (int nb = 0; nb < 4; ++nb) {
      int kvr = nb * 16 + l16;
      #pragma unroll
      for (int ks = 0; ks < 4; ++ks) {
        int dc2 = (ks * 4 + quad) ^ (kvr & 15);
        bf16x8 kb = *(const bf16x8*)&Ks[cur][(kvr * 16 + dc2) * 8];
        sacc[nb] = __builtin_amdgcn_mfma_f32_16x16x32_bf16(kb, qf[ks], sacc[nb], 0, 0, 0);
      }
    }

    float p[4][4];
    float smax = -1e30f;
    if (j == qt) {
      const int qg = qw0 + l16;
      #pragma unroll
      for (int nb = 0; nb < 4; ++nb)
        #pragma unroll
        for (int r = 0; r < 4; ++r) {
          float v = sacc[nb][r] * SC;
          if ((kv0 + nb * 16 + quad * 4 + r) > qg) v = -1e30f;
          p[nb][r] = v;
          smax = fmaxf(smax, v);
        }
    } else {
      #pragma unroll
      for (int nb = 0; nb < 4; ++nb)
        #pragma unroll
        for (int r = 0; r < 4; ++r) {
          float v = sacc[nb][r] * SC;
          p[nb][r] = v;
          smax = fmaxf(smax, v);
        }
    }
    smax = fmaxf(smax, __shfl_xor(smax, 16));
    smax = fmaxf(smax, __shfl_xor(smax, 32));

    const float mold = mrow;
    const unsigned long long grew = __ballot(smax > mold);
    const float mnew = fmaxf(mold, smax);
    mrow = mnew;

    float rs = 0.f;
    #pragma unroll
    for (int nb = 0; nb < 4; ++nb)
      #pragma unroll
      for (int r = 0; r < 4; ++r) {
        float pv = exp2f(p[nb][r] - mnew);
        p[nb][r] = pv;
        rs += pv;
      }
    rs += __shfl_xor(rs, 16);
    rs += __shfl_xor(rs, 32);

    unsigned short* pw = &Ps[wave][0];
    #pragma unroll
    for (int nb = 0; nb < 4; ++nb) {
      __hip_bfloat162 lo = __float22bfloat162_rn(make_float2(p[nb][0], p[nb][1]));
      __hip_bfloat162 hi = __float22bfloat162_rn(make_float2(p[nb][2], p[nb][3]));
      ushort4 w;
      w.x = *(unsigned short*)&lo.x; w.y = *(unsigned short*)&lo.y;
      w.z = *(unsigned short*)&hi.x; w.w = *(unsigned short*)&hi.y;
      *(ushort4*)&pw[l16 * 72 + nb * 16 + quad * 4] = w;
    }

    if (grew) {   // wave-uniform
      float alpha = exp2f(mold - mnew);
      lrow = lrow * alpha + rs;
      #pragma unroll
      for (int r = 0; r < 4; ++r) {
        float av = __shfl(alpha, quad * 4 + r, 16);
        #pragma unroll
        for (int db = 0; db < 8; ++db) o[db][r] *= av;
      }
    } else {
      lrow += rs;
    }

    asm volatile("s_waitcnt lgkmcnt(0)" ::: "memory");
    bf16x8 pa[2];
    #pragma unroll
    for (int ks2 = 0; ks2 < 2; ++ks2)
      pa[ks2] = *(const bf16x8*)&pw[l16 * 72 + ks2 * 32 + quad * 8];

    #pragma unroll
    for (int db = 0; db < 8; ++db) {
      int d = db * 16 + l16;
      #pragma unroll
      for (int ks2 = 0; ks2 < 2; ++ks2) {
        int dc = (ks2 * 4 + quad) ^ (d & 7);
        bf16x8 vb = *(const bf16x8*)&Vs[cur][(d * 8 + dc) * 8];
        o[db] = __builtin_amdgcn_mfma_f32_16x16x32_bf16(pa[ks2], vb, o[db], 0, 0, 0);
      }
    }
  };

  for (int j = 0; j <= qtB; ++j) {
    const int cur = j & 1;
    __syncthreads();   // buf[cur] ready; all reads of buf[cur^1] complete

    if (j < qtB) {     // prefetch tile j+1, overlapped with compute below
      const int kv1 = (j + 1) * 64;
      #pragma unroll
      for (int i = 0; i < 4; ++i) {
        int cc = i * 256 + t;
        int kv = cc >> 4, sc = cc & 15;
        int dc = sc ^ (kv & 15);
        gld16(qk + (size_t)(rowbase + kv1 + kv) * 4096 + EMBED + hq + dc * 8, &Ks[cur ^ 1][cc * 8]);
      }
      #pragma unroll
      for (int i = 0; i < 4; ++i) {
        int cc = i * 256 + t;
        int d = cc >> 3, c = cc & 7;
        int dc = c ^ (d & 7);
        gld16(vbase + (size_t)d * SEQ + kv1 + dc * 8, &Vs[cur ^ 1][cc * 8]);
      }
    }

    const int kv0 = j * 64;
    process(j, cur, kv0, qfB, oB, mB, lB, qtB, qw0B);
    if (j <= qtA)
      process(j, cur, kv0, qfA, oA, mA, lA, qtA, qw0A);
  }

  // epilogue: rows q = quad*4+r, cols d = db*16+l16
  #pragma unroll
  for (int r = 0; r < 4; ++r) {
    float lrB = __shfl(lB, quad * 4 + r, 16);
    float invB = 1.0f / lrB;
    size_t rowB = rowbase + qw0B + quad * 4 + r;
    #pragma unroll
    for (int db = 0; db < 8; ++db)
      outb[rowB * EMBED + hq + db * 16 + l16] = f2bf(oB[db][r] * invB);
    float lrA = __shfl(lA, quad * 4 + r, 16);
    float invA = 1.0f / lrA;
    size_t rowA = rowbase + qw0A + quad * 4 + r;
    #pragma unroll
    for (int db = 0; db < 8; ++db)
      outb[rowA * EMBED + hq + db * 16 + l16] = f2bf(oA[db][r] * invA);
  }
}

extern "C" void kernel_launch(void* const* d_in, const int* in_sizes, int n_in,
                              void* d_out, int out_size, void* d_ws, size_t ws_size,
                              hipStream_t stream) {
  const float* x    = (const float*)d_in[0];
  const float* Wqkv = (const float*)d_in[1];
  const float* bqkv = (const float*)d_in[2];
  const float* Wout = (const float*)d_in[3];
  const float* bout = (const float*)d_in[4];
  float* out = (float*)d_out;

  unsigned short* xb    = (unsigned short*)d_ws;
  unsigned short* wqkvT = xb    + (size_t)ROWS * EMBED;    // [6144][2048]
  unsigned short* woutT = wqkvT + (size_t)EMBED * QKVC;    // [2048][2048]
  unsigned short* qkb   = woutT + (size_t)EMBED * EMBED;   // [4096][4096] Q|K
  unsigned short* vtb   = qkb   + (size_t)ROWS * 4096;     // [32*128][2048] V^T
  unsigned short* attnb = vtb   + (size_t)32 * HDIM * SEQ; // [4096][2048]

  cast_kernel<<<dim3((ROWS * EMBED / 4 + 255) / 256), 256, 0, stream>>>(x, xb, ROWS * EMBED / 4);
  transpose_cast_kernel<<<dim3(QKVC / 32, EMBED / 32), 256, 0, stream>>>(Wqkv, wqkvT, EMBED, QKVC);
  transpose_cast_kernel<<<dim3(EMBED / 32, EMBED / 32), 256, 0, stream>>>(Wout, woutT, EMBED, EMBED);

  gemm_kernel<0><<<dim3(QKVC / 128, ROWS / 128), 256, 0, stream>>>(
      xb, wqkvT, bqkv, qkb, vtb, nullptr, ROWS, QKVC, EMBED);

  attn_kernel<<<dim3(32, 16), 256, 0, stream>>>(qkb, vtb, attnb);

  gemm_kernel<1><<<dim3(EMBED / 128, ROWS / 128), 256, 0, stream>>>(
      attnb, woutT, bout, nullptr, nullptr, out, ROWS, EMBED, EMBED);
}